// Round 6
// baseline (225.423 us; speedup 1.0000x reference)
//
#include <hip/hip_runtime.h>
#include <hip/hip_fp16.h>

// ---------------- problem constants ----------------
#define BATCH 64
#define HH    28
#define WW2   28
#define HWPX  784          // 28*28
#define PTOT  50176        // 64*784
#define CIN   384
#define DIM   96
#define MDIM  64
#define JTOT  82944        // DIM*DIM*9
#define WSAMP 82944        // per-sample conv weights (96*864)

// ws layout (bytes)
#define XD_OFF 0u                       // P*96 f16 = 9,633,792
#define Y_OFF  9633792u                 // P*96 f16
#define WP_OFF 19267584u                // 64*82944 f16 = 10,616,832
#define HS_OFF 29884416u                // 64*64 f32
#define Z_OFF  29900800u                // 64*64 f32
#define WUT_OFF 29917184u               // 384*96 f16 = 73,728
// Wt (f16 [160][384] = 122,880 B) lives at WP_OFF: consumed by k1 BEFORE
// k2b overwrites the wperm region. Single stream -> deterministic.

typedef _Float16 f16x8 __attribute__((ext_vector_type(8)));
typedef _Float16 f16x4 __attribute__((ext_vector_type(4)));
typedef float f32x4 __attribute__((ext_vector_type(4)));

__device__ __forceinline__ float qgelu(float v) {
    return v / (1.f + __expf(-1.702f * v));
}

// ============================================================
// K0: convert [Wm1 | Wd] -> Wt f16 [o=160][k=384]
//     and Wu [96][384] -> WuT f16 [c=384][d=96]
// ============================================================
__global__ void k0_wcvt(const float* __restrict__ Wm1,
                        const float* __restrict__ Wd,
                        const float* __restrict__ Wu,
                        _Float16* __restrict__ Wt,
                        _Float16* __restrict__ WuT)
{
    int i = blockIdx.x * 256 + threadIdx.x;   // < 98304
    if (i < 61440) {
        int o = i / CIN, k = i - o * CIN;
        float v = (o < MDIM) ? Wm1[k * MDIM + o] : Wd[k * DIM + (o - MDIM)];
        Wt[i] = (_Float16)v;
    } else {
        int j = i - 61440;                    // < 36864
        int c = j / DIM, d = j - c * DIM;
        WuT[j] = (_Float16)Wu[d * CIN + c];
    }
}

// ============================================================
// K1: MFMA GEMM  C[P,160] = f16(x)[P,384] @ Wt^T, fused epilogues.
// grid 784 = 392 m-tiles x 2 n-halves (M=128, N=80). block 512 (8 waves,
// wave w owns rows w*16..w*16+15, all 80 cols -> 5 MFMA/chunk/wave).
// 3-deep register prefetch + double-buffered LDS: chunk kc+3 issued at
// iter kc, written to LDS at iter kc+2 -> ~2 iterations of latency cover.
// nb=0: cols 0..63 meta (relu+reduce->hsum), cols 64..79 -> xd[:,0:16)
// nb=1: cols 80..159 -> xd[:,16:96)
// ============================================================
__global__ __launch_bounds__(512, 4) void k1_mfma(
    const float* __restrict__ x, const _Float16* __restrict__ Wt,
    const float* __restrict__ bm1, const float* __restrict__ bd,
    float* __restrict__ hsum, __half* __restrict__ xd)
{
    __shared__ char smem[30464];
    _Float16* As  = (_Float16*)smem;               // 2 x [128][36] (18432 B)
    _Float16* Bs  = (_Float16*)(smem + 18432);     // 2 x [80][36]  (11520 B)
    float*   hred = (float*)(smem + 29952);        // [2][64]
    _Float16* xds = (_Float16*)smem;               // epilogue repack

    const int t = threadIdx.x;
    const int bid = blockIdx.x;                    // 784
    const int mt = bid >> 1, nb = bid & 1;
    const int p0 = mt * 128;
    const int ncol0 = nb * 80;

    const int lane = t & 63, w = t >> 6;
    const int rl = lane & 15, q = lane >> 4;

    // staging: A 128 rows x 32 f32 (4 thr/row), B 80 rows x 32 f16 (4 thr/row)
    const int arow = t >> 2, acol = (t & 3) * 8;
    const float* ag = x + (size_t)(p0 + arow) * CIN + acol;
    const bool bact = (t < 320);
    const int brow = t >> 2, bcol = (t & 3) * 8;
    const _Float16* bg = Wt + (size_t)(ncol0 + (bact ? brow : 0)) * CIN + bcol;

    float4 ra[3][2];
    uint4  rb[3];

#define LOADC(s, kc_) do {                                        \
    ra[s][0] = *(const float4*)(ag + (kc_) * 32);                 \
    ra[s][1] = *(const float4*)(ag + (kc_) * 32 + 4);             \
    if (bact) rb[s] = *(const uint4*)(bg + (kc_) * 32);           \
} while (0)

#define WRITEC(buf, s) do {                                       \
    f16x8 h;                                                      \
    h[0] = (_Float16)ra[s][0].x; h[1] = (_Float16)ra[s][0].y;     \
    h[2] = (_Float16)ra[s][0].z; h[3] = (_Float16)ra[s][0].w;     \
    h[4] = (_Float16)ra[s][1].x; h[5] = (_Float16)ra[s][1].y;     \
    h[6] = (_Float16)ra[s][1].z; h[7] = (_Float16)ra[s][1].w;     \
    *(f16x8*)(As + (buf) * 4608 + arow * 36 + acol) = h;          \
    if (bact)                                                     \
        *(uint4*)(Bs + (buf) * 2880 + brow * 36 + bcol) = rb[s];  \
} while (0)

    f32x4 acc[5];
    #pragma unroll
    for (int nf = 0; nf < 5; ++nf) acc[nf] = (f32x4){0.f, 0.f, 0.f, 0.f};

    LOADC(0, 0); LOADC(1, 1); LOADC(2, 2);
    WRITEC(0, 0);
    __syncthreads();

    #pragma unroll
    for (int kc = 0; kc < 12; ++kc) {
        const int cur = kc & 1;

        f16x8 av = *(f16x8*)(As + cur * 4608 + (w * 16 + rl) * 36 + q * 8);
        f16x8 bv[5];
        #pragma unroll
        for (int nf = 0; nf < 5; ++nf)
            bv[nf] = *(f16x8*)(Bs + cur * 2880 + (nf * 16 + rl) * 36 + q * 8);

        if (kc + 3 < 12) LOADC(kc % 3, kc + 3);

        #pragma unroll
        for (int nf = 0; nf < 5; ++nf)
            acc[nf] = __builtin_amdgcn_mfma_f32_16x16x32_f16(
                av, bv[nf], acc[nf], 0, 0, 0);

        if (kc + 1 < 12) {
            WRITEC(cur ^ 1, (kc + 1) % 3);
            __syncthreads();
        }
    }
#undef LOADC
#undef WRITEC

    // ---- epilogue ----
    __syncthreads();                   // LDS about to be reused
    if (t < 128) hred[t] = 0.f;
    __syncthreads();

    const int s0 = p0 / HWPX, s_last = (p0 + 127) / HWPX;
    #pragma unroll
    for (int nf = 0; nf < 5; ++nf) {
        const int col = ncol0 + nf * 16 + rl;
        #pragma unroll
        for (int j = 0; j < 4; ++j) {
            const int rr = w * 16 + q * 4 + j;
            float v = acc[nf][j];
            if (nb == 0 && col < 64) {
                v = fmaxf(v + bm1[col], 0.f);
                int sloc = (p0 + rr) / HWPX - s0;
                atomicAdd(&hred[sloc * 64 + col], v);
            } else {
                int e = col - 64;                   // global xd col
                float g = qgelu(v + bd[e]);
                if (nb == 0) xds[rr * 16 + (e)] = (_Float16)g;        // e<16
                else         xds[rr * 80 + (e - 16)] = (_Float16)g;   // 0..79
            }
        }
    }
    __syncthreads();

    if (nb == 0) {
        if (t < 128) {
            int sloc = t >> 6, col = t & 63, s = s0 + sloc;
            if (s <= s_last) atomicAdd(&hsum[s * 64 + col], hred[t]);
        }
        if (t < 256) {                 // 128 rows x 16 f16 = 256 x 8
            int row = t >> 1, h8 = t & 1;
            *(uint4*)((__half*)xd + (size_t)(p0 + row) * 96 + h8 * 8) =
                *(uint4*)(xds + row * 16 + h8 * 8);
        }
    } else {
        for (int idx = t; idx < 1280; idx += 512) {  // 128 rows x 80 f16
            int row = idx / 10, q10 = idx - row * 10;
            *(uint4*)((__half*)xd + (size_t)(p0 + row) * 96 + 16 + q10 * 8) =
                *(uint4*)(xds + row * 80 + q10 * 8);
        }
    }
}

// ============================================================
// K2a: z[b][m] = emb[m] + (hsum[b]/784)@Wm2 + bm2[m]
// ============================================================
__global__ void k2a_prompt(const float* __restrict__ hsum,
                           const float* __restrict__ Wm2,
                           const float* __restrict__ bm2,
                           const float* __restrict__ emb,
                           float* __restrict__ z)
{
    int idx = blockIdx.x * 256 + threadIdx.x;   // 4096
    int b = idx >> 6, m = idx & 63;
    float acc = 0.f;
    #pragma unroll 8
    for (int d = 0; d < 64; ++d) acc += hsum[b * 64 + d] * Wm2[d * 64 + m];
    z[idx] = emb[m] + acc * (1.f / 784.f) + bm2[m];
}

// ============================================================
// K2b: wflat[b][j] = z[b]@Wh[:,j] + bh[j], stored PERMUTED as
//      wperm[b][o][t9][i] (f16).  grid 324, block 256.
// ============================================================
__global__ __launch_bounds__(256) void k2b_hyper(
    const float* __restrict__ z, const float* __restrict__ Wh,
    const float* __restrict__ bh, __half* __restrict__ wperm)
{
    __shared__ float zs[4096];
    const int t = threadIdx.x;
    for (int idx = t; idx < 4096; idx += 256) zs[idx] = z[idx];
    const int j = blockIdx.x * 256 + t;
    float wh[64];
    #pragma unroll 8
    for (int m = 0; m < 64; ++m) wh[m] = Wh[(size_t)m * JTOT + j];
    __syncthreads();

    const int o = j / 864, rem = j % 864;
    const int i = rem / 9, t9 = rem % 9;
    const int base = o * 864 + t9 * 96 + i;
    const float bj = bh[j];
    for (int b = 0; b < 64; ++b) {
        float a = bj;
        const float4* zz = (const float4*)(zs + b * 64);
        #pragma unroll
        for (int m4 = 0; m4 < 16; ++m4) {
            float4 v = zz[m4];
            a += v.x * wh[4 * m4] + v.y * wh[4 * m4 + 1] +
                 v.z * wh[4 * m4 + 2] + v.w * wh[4 * m4 + 3];
        }
        wperm[(size_t)b * WSAMP + base] = __float2half(a);
    }
}

// ============================================================
// K3: MFMA implicit-GEMM grouped 3x3 conv + quick_gelu.
// grid 448 (XCD-grouped swizzle), block 256 (4 waves, 2m x 2n).
// ============================================================
__global__ __launch_bounds__(256) void k3_mfma(
    const __half* __restrict__ xd, const __half* __restrict__ wperm,
    __half* __restrict__ y)
{
    __shared__ __half sm[17600];                 // 35,200 B
    const int t = threadIdx.x;

    const int n = blockIdx.x;                    // 448
    const int xcd = n & 7, jj0 = n >> 3;         // jj0 < 56
    const int b = xcd * 8 + jj0 / 7;
    const int rt = jj0 % 7;
    const int h0 = rt * 4;

    if (t < 16) *(uint4*)(sm + 17472 + t * 8) = uint4{0u, 0u, 0u, 0u};
    for (int idx = t; idx < 2016; idx += 256) {
        int pix = idx / 12, q = idx - pix * 12;
        int r = pix / 28, col = pix - r * 28;
        int g = h0 - 1 + r;
        uint4 v = {0u, 0u, 0u, 0u};
        if ((unsigned)g < 28u)
            v = *(const uint4*)(xd + (size_t)(b * HWPX + g * 28 + col) * 96 + q * 8);
        *(uint4*)(sm + pix * 104 + q * 8) = v;
    }
    __syncthreads();

    const int lane = t & 63, w = t >> 6;
    const int wm = w >> 1, wn = w & 1;
    const int mloc = lane & 15, klo = (lane >> 4) * 8;
    const int base_m = wm * 64;

    int oh_[4], ow_[4]; bool pv[4];
    #pragma unroll
    for (int mf = 0; mf < 4; ++mf) {
        int p = base_m + mf * 16 + mloc;
        pv[mf] = (p < 112);
        int pp = pv[mf] ? p : 0;
        oh_[mf] = pp / 28; ow_[mf] = pp - oh_[mf] * 28;
    }
    const __half* wp = wperm + (size_t)b * WSAMP + (wn * 48 + mloc) * 864 + klo;

    f32x4 acc[4][3];
    #pragma unroll
    for (int mf = 0; mf < 4; ++mf)
        #pragma unroll
        for (int nf = 0; nf < 3; ++nf) acc[mf][nf] = (f32x4){0.f, 0.f, 0.f, 0.f};

    #pragma unroll
    for (int kh = 0; kh < 3; ++kh) {
        #pragma unroll
        for (int kw = 0; kw < 3; ++kw) {
            const int t9 = kh * 3 + kw;
            int abase[4];
            #pragma unroll
            for (int mf = 0; mf < 4; ++mf) {
                int iw = ow_[mf] + kw - 1;
                bool valid = pv[mf] && ((unsigned)iw < 28u);
                abase[mf] = valid ? ((oh_[mf] + kh) * 28 + iw) * 104 + klo
                                  : 17472 + klo;
            }
            #pragma unroll
            for (int ic = 0; ic < 3; ++ic) {
                f16x8 av[4], bv[3];
                #pragma unroll
                for (int nf = 0; nf < 3; ++nf)
                    bv[nf] = *(const f16x8*)(wp + nf * 13824 + t9 * 96 + ic * 32);
                #pragma unroll
                for (int mf = 0; mf < 4; ++mf)
                    av[mf] = *(const f16x8*)(sm + abase[mf] + ic * 32);
                #pragma unroll
                for (int mf = 0; mf < 4; ++mf)
                    #pragma unroll
                    for (int nf = 0; nf < 3; ++nf)
                        acc[mf][nf] = __builtin_amdgcn_mfma_f32_16x16x32_f16(
                            av[mf], bv[nf], acc[mf][nf], 0, 0, 0);
            }
        }
    }
    __syncthreads();

    #pragma unroll
    for (int mf = 0; mf < 4; ++mf) {
        #pragma unroll
        for (int nf = 0; nf < 3; ++nf) {
            const int o = wn * 48 + nf * 16 + mloc;
            #pragma unroll
            for (int j = 0; j < 4; ++j) {
                int p = base_m + mf * 16 + (lane >> 4) * 4 + j;
                if (p < 112)
                    sm[p * 104 + o] = __float2half(qgelu(acc[mf][nf][j]));
            }
        }
    }
    __syncthreads();
    for (int idx = t; idx < 1344; idx += 256) {
        int pix = idx / 12, q = idx - pix * 12;
        *(uint4*)(y + (size_t)(b * HWPX + h0 * 28 + pix) * 96 + q * 8) =
            *(uint4*)(sm + pix * 104 + q * 8);
    }
}

// ============================================================
// K4: MFMA GEMM  out[P,384] = y[P,96] @ Wu + bu (f32 out).
// grid 392, block 512 (8 waves 2m x 4n). Tile M=128, N=384, K=96.
// ============================================================
__global__ __launch_bounds__(512, 2) void k4_mfma(
    const __half* __restrict__ y, const _Float16* __restrict__ WuT,
    const float* __restrict__ bu, float* __restrict__ out)
{
    __shared__ __half ys[128 * 104];             // 26,624 B
    const int t = threadIdx.x;
    const int p0 = blockIdx.x * 128;

    #pragma unroll
    for (int i = 0; i < 3; ++i) {
        int idx = t + i * 512;                   // < 1536
        int pix = idx / 12, q = idx - pix * 12;
        *(uint4*)(ys + pix * 104 + q * 8) =
            *(const uint4*)(y + (size_t)(p0 + pix) * 96 + q * 8);
    }

    const int lane = t & 63, w = t >> 6;
    const int wm = w >> 2, wn = w & 3;           // 2m x 4n
    const int mloc = lane & 15, klo = (lane >> 4) * 8;

    float bcol[6];
    #pragma unroll
    for (int nf = 0; nf < 6; ++nf) bcol[nf] = bu[wn * 96 + nf * 16 + mloc];
    __syncthreads();

    f32x4 acc[4][6];
    #pragma unroll
    for (int mf = 0; mf < 4; ++mf)
        #pragma unroll
        for (int nf = 0; nf < 6; ++nf) acc[mf][nf] = (f32x4){0.f, 0.f, 0.f, 0.f};

    #pragma unroll
    for (int kc = 0; kc < 3; ++kc) {
        f16x8 av[4], bv[6];
        #pragma unroll
        for (int nf = 0; nf < 6; ++nf)
            bv[nf] = *(const f16x8*)(WuT + (wn * 96 + nf * 16 + mloc) * 96 + kc * 32 + klo);
        #pragma unroll
        for (int mf = 0; mf < 4; ++mf)
            av[mf] = *(const f16x8*)(ys + (wm * 64 + mf * 16 + mloc) * 104 + kc * 32 + klo);
        #pragma unroll
        for (int mf = 0; mf < 4; ++mf)
            #pragma unroll
            for (int nf = 0; nf < 6; ++nf)
                acc[mf][nf] = __builtin_amdgcn_mfma_f32_16x16x32_f16(
                    av[mf], bv[nf], acc[mf][nf], 0, 0, 0);
    }

    #pragma unroll
    for (int mf = 0; mf < 4; ++mf) {
        #pragma unroll
        for (int nf = 0; nf < 6; ++nf) {
            const int c = wn * 96 + nf * 16 + mloc;
            #pragma unroll
            for (int j = 0; j < 4; ++j) {
                int p = p0 + wm * 64 + mf * 16 + (lane >> 4) * 4 + j;
                out[(size_t)p * CIN + c] = acc[mf][nf][j] + bcol[nf];
            }
        }
    }
}

// ============================================================
extern "C" void kernel_launch(void* const* d_in, const int* in_sizes, int n_in,
                              void* d_out, int out_size, void* d_ws, size_t ws_size,
                              hipStream_t stream)
{
    const float* x   = (const float*)d_in[0];
    const float* Wd  = (const float*)d_in[1];
    const float* bd  = (const float*)d_in[2];
    const float* Wm1 = (const float*)d_in[3];
    const float* bm1 = (const float*)d_in[4];
    const float* Wm2 = (const float*)d_in[5];
    const float* bm2 = (const float*)d_in[6];
    const float* Wh  = (const float*)d_in[7];
    const float* bh  = (const float*)d_in[8];
    const float* emb = (const float*)d_in[9];
    const float* Wu  = (const float*)d_in[10];
    const float* bu  = (const float*)d_in[11];
    float* out = (float*)d_out;

    char* ws = (char*)d_ws;
    __half*   xd    = (__half*)(ws + XD_OFF);
    __half*   ybuf  = (__half*)(ws + Y_OFF);
    __half*   wperm = (__half*)(ws + WP_OFF);
    float*    hsum  = (float*)(ws + HS_OFF);
    float*    z     = (float*)(ws + Z_OFF);
    _Float16* Wt    = (_Float16*)(ws + WP_OFF);   // transient, consumed before k2b
    _Float16* WuT   = (_Float16*)(ws + WUT_OFF);

    hipMemsetAsync(hsum, 0, 64 * 64 * sizeof(float), stream);

    k0_wcvt<<<384, 256, 0, stream>>>(Wm1, Wd, Wu, Wt, WuT);
    k1_mfma<<<784, 512, 0, stream>>>(x, Wt, bm1, bd, hsum, xd);
    k2a_prompt<<<16, 256, 0, stream>>>(hsum, Wm2, bm2, emb, z);
    k2b_hyper<<<324, 256, 0, stream>>>(z, Wh, bh, wperm);
    k3_mfma<<<448, 256, 0, stream>>>(xd, wperm, ybuf);
    k4_mfma<<<392, 512, 0, stream>>>(ybuf, WuT, bu, out);
}

// Round 7
// 151.140 us; speedup vs baseline: 1.4915x; 1.4915x over previous
//
#include <hip/hip_runtime.h>
#include <hip/hip_fp16.h>

// ---------------- problem constants ----------------
#define BATCH 64
#define HH    28
#define WW2   28
#define HWPX  784          // 28*28
#define PTOT  50176        // 64*784
#define CIN   384
#define DIM   96
#define MDIM  64
#define JTOT  82944        // DIM*DIM*9
#define WSAMP 82944        // per-sample conv weights (96*864)

// ws layout (bytes)
#define XD_OFF 0u                       // P*96 f16 = 9,633,792
#define Y_OFF  9633792u                 // P*96 f16
#define WP_OFF 19267584u                // 64*82944 f16 = 10,616,832
#define HS_OFF 29884416u                // 64*64 f32
#define Z_OFF  29900800u                // 64*64 f32
#define WUT_OFF 29917184u               // 384*96 f16 = 73,728
// Wt (f16 [160][384] = 122,880 B) lives at WP_OFF: consumed by k1 BEFORE
// k2b overwrites the wperm region. Single stream -> deterministic.

typedef _Float16 f16x8 __attribute__((ext_vector_type(8)));
typedef _Float16 f16x4 __attribute__((ext_vector_type(4)));
typedef float f32x4 __attribute__((ext_vector_type(4)));

__device__ __forceinline__ float qgelu(float v) {
    return v / (1.f + __expf(-1.702f * v));
}

// ============================================================
// K0: convert [Wm1 | Wd] -> Wt f16 [o=160][k=384]
//     and Wu [96][384] -> WuT f16 [c=384][d=96]
// ============================================================
__global__ void k0_wcvt(const float* __restrict__ Wm1,
                        const float* __restrict__ Wd,
                        const float* __restrict__ Wu,
                        _Float16* __restrict__ Wt,
                        _Float16* __restrict__ WuT)
{
    int i = blockIdx.x * 256 + threadIdx.x;   // < 98304
    if (i < 61440) {
        int o = i / CIN, k = i - o * CIN;
        float v = (o < MDIM) ? Wm1[k * MDIM + o] : Wd[k * DIM + (o - MDIM)];
        Wt[i] = (_Float16)v;
    } else {
        int j = i - 61440;                    // < 36864
        int c = j / DIM, d = j - c * DIM;
        WuT[j] = (_Float16)Wu[d * CIN + c];
    }
}

// ============================================================
// K1: MFMA GEMM  C[P,160] = f16(x)[P,384] @ Wt^T, fused epilogues:
//   cols 0..63  : relu(+bm1) -> per-sample sum -> hsum (atomics)
//   cols 64..159: quick_gelu(+bd) -> xd f16
// grid 392, block 512 (8 waves: 4m x 2n). Tile M=128, N=160, KC=32.
// r3 structure + double-buffered LDS + 2-chunk-ahead register prefetch:
// loads for chunk kc+2 issued at iter kc, LDS-written at end of iter kc+1
// -> ~1.5 iterations of HBM latency cover, one barrier per iter.
// ============================================================
__global__ __launch_bounds__(512, 2) void k1_mfma(
    const float* __restrict__ x, const _Float16* __restrict__ Wt,
    const float* __restrict__ bm1, const float* __restrict__ bd,
    float* __restrict__ hsum, __half* __restrict__ xd)
{
    __shared__ char smem[46592];
    _Float16* As  = (_Float16*)smem;               // 2 x [128][40] (20480 B)
    _Float16* Bs  = (_Float16*)(smem + 20480);     // 2 x [160][40] (25600 B)
    float*   hred = (float*)(smem + 46080);        // [2][64] f32
    _Float16* xds = (_Float16*)smem;               // epilogue [128][96]

    const int t = threadIdx.x;
    const int p0 = blockIdx.x * 128;
    const int lane = t & 63, w = t >> 6;
    const int wm = w >> 1, wn = w & 1;             // 4m x 2n wave grid
    const int rl = lane & 15, q = lane >> 4;

    // staging indices (A-variant, proven coalescing)
    const int ar0 = t >> 3, aq0 = t & 7;           // A rows 0..63 / +64
    const int br0 = t >> 2, bq0 = t & 3;           // B rows 0..127 / +128 (t<128)

    const float*    ag0 = x + (size_t)(p0 + ar0) * CIN + aq0 * 4;
    const float*    ag1 = ag0 + (size_t)64 * CIN;
    const _Float16* bg0 = Wt + br0 * CIN + bq0 * 8;
    const _Float16* bg1 = Wt + (br0 + 128) * CIN + bq0 * 8;

    float4 ra[2][2];
    uint4  rb[2][2];

#define LOADC(s, kc_) do {                                        \
    ra[s][0] = *(const float4*)(ag0 + (kc_) * 32);                \
    ra[s][1] = *(const float4*)(ag1 + (kc_) * 32);                \
    rb[s][0] = *(const uint4*)(bg0 + (kc_) * 32);                 \
    if (t < 128) rb[s][1] = *(const uint4*)(bg1 + (kc_) * 32);    \
} while (0)

#define WRITEC(buf, s) do {                                       \
    f16x4 h0, h1;                                                 \
    h0[0] = (_Float16)ra[s][0].x; h0[1] = (_Float16)ra[s][0].y;   \
    h0[2] = (_Float16)ra[s][0].z; h0[3] = (_Float16)ra[s][0].w;   \
    h1[0] = (_Float16)ra[s][1].x; h1[1] = (_Float16)ra[s][1].y;   \
    h1[2] = (_Float16)ra[s][1].z; h1[3] = (_Float16)ra[s][1].w;   \
    *(f16x4*)(As + (buf) * 5120 + ar0 * 40 + aq0 * 4) = h0;       \
    *(f16x4*)(As + (buf) * 5120 + (ar0 + 64) * 40 + aq0 * 4) = h1;\
    *(uint4*)(Bs + (buf) * 6400 + br0 * 40 + bq0 * 8) = rb[s][0]; \
    if (t < 128)                                                  \
        *(uint4*)(Bs + (buf) * 6400 + (br0 + 128) * 40 + bq0 * 8) = rb[s][1]; \
} while (0)

    f32x4 acc[2][5];
    #pragma unroll
    for (int mf = 0; mf < 2; ++mf)
        #pragma unroll
        for (int nf = 0; nf < 5; ++nf) acc[mf][nf] = (f32x4){0.f, 0.f, 0.f, 0.f};

    // prologue: chunk0+1 loads in flight; chunk0 -> LDS buf0
    LOADC(0, 0);
    LOADC(1, 1);
    WRITEC(0, 0);
    __syncthreads();

    #pragma unroll
    for (int kc = 0; kc < 12; ++kc) {
        const int cur = kc & 1;

        f16x8 av[2], bv[5];
        av[0] = *(f16x8*)(As + cur * 5120 + (wm * 32 + rl) * 40 + q * 8);
        av[1] = *(f16x8*)(As + cur * 5120 + (wm * 32 + 16 + rl) * 40 + q * 8);
        #pragma unroll
        for (int nf = 0; nf < 5; ++nf)
            bv[nf] = *(f16x8*)(Bs + cur * 6400 + (wn * 80 + nf * 16 + rl) * 40 + q * 8);

        if (kc + 2 < 12) LOADC(kc & 1, kc + 2);   // reg slot kc%2 is free now

        #pragma unroll
        for (int mf = 0; mf < 2; ++mf)
            #pragma unroll
            for (int nf = 0; nf < 5; ++nf)
                acc[mf][nf] = __builtin_amdgcn_mfma_f32_16x16x32_f16(
                    av[mf], bv[nf], acc[mf][nf], 0, 0, 0);

        if (kc + 1 < 12) {
            WRITEC(cur ^ 1, (kc + 1) & 1);        // chunk kc+1 -> other buffer
            __syncthreads();
        }
    }
#undef LOADC
#undef WRITEC

    // ---- epilogue ----
    if (t < 128) hred[t] = 0.f;
    __syncthreads();   // orders: all frag-reads done; xds writes may begin

    const int s0 = p0 / HWPX, s_last = (p0 + 127) / HWPX;
    #pragma unroll
    for (int mf = 0; mf < 2; ++mf) {
        #pragma unroll
        for (int nf = 0; nf < 5; ++nf) {
            const int col = wn * 80 + nf * 16 + rl;
            #pragma unroll
            for (int j = 0; j < 4; ++j) {
                const int rr = wm * 32 + mf * 16 + q * 4 + j;
                float v = acc[mf][nf][j];
                if (col < 64) {
                    v = fmaxf(v + bm1[col], 0.f);
                    int sloc = (p0 + rr) / HWPX - s0;
                    atomicAdd(&hred[sloc * 64 + col], v);
                } else {
                    int e = col - 64;
                    xds[rr * 96 + e] = (_Float16)qgelu(v + bd[e]);
                }
            }
        }
    }
    __syncthreads();

    if (t < 128) {
        int sloc = t >> 6, col = t & 63, s = s0 + sloc;
        if (s <= s_last) atomicAdd(&hsum[s * 64 + col], hred[t]);
    }
    #pragma unroll
    for (int i = 0; i < 3; ++i) {
        int e = t + i * 512;                       // < 1536 uint4
        *(uint4*)((__half*)xd + (size_t)p0 * 96 + e * 8) = *(uint4*)(xds + e * 8);
    }
}

// ============================================================
// K2a: z[b][m] = emb[m] + (hsum[b]/784)@Wm2 + bm2[m]
// ============================================================
__global__ void k2a_prompt(const float* __restrict__ hsum,
                           const float* __restrict__ Wm2,
                           const float* __restrict__ bm2,
                           const float* __restrict__ emb,
                           float* __restrict__ z)
{
    int idx = blockIdx.x * 256 + threadIdx.x;   // 4096
    int b = idx >> 6, m = idx & 63;
    float acc = 0.f;
    #pragma unroll 8
    for (int d = 0; d < 64; ++d) acc += hsum[b * 64 + d] * Wm2[d * 64 + m];
    z[idx] = emb[m] + acc * (1.f / 784.f) + bm2[m];
}

// ============================================================
// K2b: wflat[b][j] = z[b]@Wh[:,j] + bh[j], stored PERMUTED as
//      wperm[b][o][t9][i] (f16).  grid 324, block 256.
// ============================================================
__global__ __launch_bounds__(256) void k2b_hyper(
    const float* __restrict__ z, const float* __restrict__ Wh,
    const float* __restrict__ bh, __half* __restrict__ wperm)
{
    __shared__ float zs[4096];
    const int t = threadIdx.x;
    for (int idx = t; idx < 4096; idx += 256) zs[idx] = z[idx];
    const int j = blockIdx.x * 256 + t;
    float wh[64];
    #pragma unroll 8
    for (int m = 0; m < 64; ++m) wh[m] = Wh[(size_t)m * JTOT + j];
    __syncthreads();

    const int o = j / 864, rem = j % 864;
    const int i = rem / 9, t9 = rem % 9;
    const int base = o * 864 + t9 * 96 + i;
    const float bj = bh[j];
    for (int b = 0; b < 64; ++b) {
        float a = bj;
        const float4* zz = (const float4*)(zs + b * 64);
        #pragma unroll
        for (int m4 = 0; m4 < 16; ++m4) {
            float4 v = zz[m4];
            a += v.x * wh[4 * m4] + v.y * wh[4 * m4 + 1] +
                 v.z * wh[4 * m4 + 2] + v.w * wh[4 * m4 + 3];
        }
        wperm[(size_t)b * WSAMP + base] = __float2half(a);
    }
}

// ============================================================
// K3: MFMA implicit-GEMM grouped 3x3 conv + quick_gelu.
// grid 448 (XCD-grouped swizzle), block 256 (4 waves, 2m x 2n).
// ============================================================
__global__ __launch_bounds__(256) void k3_mfma(
    const __half* __restrict__ xd, const __half* __restrict__ wperm,
    __half* __restrict__ y)
{
    __shared__ __half sm[17600];                 // 35,200 B
    const int t = threadIdx.x;

    const int n = blockIdx.x;                    // 448
    const int xcd = n & 7, jj0 = n >> 3;         // jj0 < 56
    const int b = xcd * 8 + jj0 / 7;
    const int rt = jj0 % 7;
    const int h0 = rt * 4;

    if (t < 16) *(uint4*)(sm + 17472 + t * 8) = uint4{0u, 0u, 0u, 0u};
    for (int idx = t; idx < 2016; idx += 256) {
        int pix = idx / 12, q = idx - pix * 12;
        int r = pix / 28, col = pix - r * 28;
        int g = h0 - 1 + r;
        uint4 v = {0u, 0u, 0u, 0u};
        if ((unsigned)g < 28u)
            v = *(const uint4*)(xd + (size_t)(b * HWPX + g * 28 + col) * 96 + q * 8);
        *(uint4*)(sm + pix * 104 + q * 8) = v;
    }
    __syncthreads();

    const int lane = t & 63, w = t >> 6;
    const int wm = w >> 1, wn = w & 1;
    const int mloc = lane & 15, klo = (lane >> 4) * 8;
    const int base_m = wm * 64;

    int oh_[4], ow_[4]; bool pv[4];
    #pragma unroll
    for (int mf = 0; mf < 4; ++mf) {
        int p = base_m + mf * 16 + mloc;
        pv[mf] = (p < 112);
        int pp = pv[mf] ? p : 0;
        oh_[mf] = pp / 28; ow_[mf] = pp - oh_[mf] * 28;
    }
    const __half* wp = wperm + (size_t)b * WSAMP + (wn * 48 + mloc) * 864 + klo;

    f32x4 acc[4][3];
    #pragma unroll
    for (int mf = 0; mf < 4; ++mf)
        #pragma unroll
        for (int nf = 0; nf < 3; ++nf) acc[mf][nf] = (f32x4){0.f, 0.f, 0.f, 0.f};

    #pragma unroll
    for (int kh = 0; kh < 3; ++kh) {
        #pragma unroll
        for (int kw = 0; kw < 3; ++kw) {
            const int t9 = kh * 3 + kw;
            int abase[4];
            #pragma unroll
            for (int mf = 0; mf < 4; ++mf) {
                int iw = ow_[mf] + kw - 1;
                bool valid = pv[mf] && ((unsigned)iw < 28u);
                abase[mf] = valid ? ((oh_[mf] + kh) * 28 + iw) * 104 + klo
                                  : 17472 + klo;
            }
            #pragma unroll
            for (int ic = 0; ic < 3; ++ic) {
                f16x8 av[4], bv[3];
                #pragma unroll
                for (int nf = 0; nf < 3; ++nf)
                    bv[nf] = *(const f16x8*)(wp + nf * 13824 + t9 * 96 + ic * 32);
                #pragma unroll
                for (int mf = 0; mf < 4; ++mf)
                    av[mf] = *(const f16x8*)(sm + abase[mf] + ic * 32);
                #pragma unroll
                for (int mf = 0; mf < 4; ++mf)
                    #pragma unroll
                    for (int nf = 0; nf < 3; ++nf)
                        acc[mf][nf] = __builtin_amdgcn_mfma_f32_16x16x32_f16(
                            av[mf], bv[nf], acc[mf][nf], 0, 0, 0);
            }
        }
    }
    __syncthreads();

    #pragma unroll
    for (int mf = 0; mf < 4; ++mf) {
        #pragma unroll
        for (int nf = 0; nf < 3; ++nf) {
            const int o = wn * 48 + nf * 16 + mloc;
            #pragma unroll
            for (int j = 0; j < 4; ++j) {
                int p = base_m + mf * 16 + (lane >> 4) * 4 + j;
                if (p < 112)
                    sm[p * 104 + o] = __float2half(qgelu(acc[mf][nf][j]));
            }
        }
    }
    __syncthreads();
    for (int idx = t; idx < 1344; idx += 256) {
        int pix = idx / 12, q = idx - pix * 12;
        *(uint4*)(y + (size_t)(b * HWPX + h0 * 28 + pix) * 96 + q * 8) =
            *(uint4*)(sm + pix * 104 + q * 8);
    }
}

// ============================================================
// K4: MFMA GEMM  out[P,384] = y[P,96] @ Wu + bu (f32 out).
// grid 392, block 512 (8 waves 2m x 4n). Tile M=128, N=384, K=96.
// ============================================================
__global__ __launch_bounds__(512, 2) void k4_mfma(
    const __half* __restrict__ y, const _Float16* __restrict__ WuT,
    const float* __restrict__ bu, float* __restrict__ out)
{
    __shared__ __half ys[128 * 104];             // 26,624 B
    const int t = threadIdx.x;
    const int p0 = blockIdx.x * 128;

    #pragma unroll
    for (int i = 0; i < 3; ++i) {
        int idx = t + i * 512;                   // < 1536
        int pix = idx / 12, q = idx - pix * 12;
        *(uint4*)(ys + pix * 104 + q * 8) =
            *(const uint4*)(y + (size_t)(p0 + pix) * 96 + q * 8);
    }

    const int lane = t & 63, w = t >> 6;
    const int wm = w >> 2, wn = w & 3;           // 2m x 4n
    const int mloc = lane & 15, klo = (lane >> 4) * 8;

    float bcol[6];
    #pragma unroll
    for (int nf = 0; nf < 6; ++nf) bcol[nf] = bu[wn * 96 + nf * 16 + mloc];
    __syncthreads();

    f32x4 acc[4][6];
    #pragma unroll
    for (int mf = 0; mf < 4; ++mf)
        #pragma unroll
        for (int nf = 0; nf < 6; ++nf) acc[mf][nf] = (f32x4){0.f, 0.f, 0.f, 0.f};

    #pragma unroll
    for (int kc = 0; kc < 3; ++kc) {
        f16x8 av[4], bv[6];
        #pragma unroll
        for (int nf = 0; nf < 6; ++nf)
            bv[nf] = *(const f16x8*)(WuT + (wn * 96 + nf * 16 + mloc) * 96 + kc * 32 + klo);
        #pragma unroll
        for (int mf = 0; mf < 4; ++mf)
            av[mf] = *(const f16x8*)(ys + (wm * 64 + mf * 16 + mloc) * 104 + kc * 32 + klo);
        #pragma unroll
        for (int mf = 0; mf < 4; ++mf)
            #pragma unroll
            for (int nf = 0; nf < 6; ++nf)
                acc[mf][nf] = __builtin_amdgcn_mfma_f32_16x16x32_f16(
                    av[mf], bv[nf], acc[mf][nf], 0, 0, 0);
    }

    #pragma unroll
    for (int mf = 0; mf < 4; ++mf) {
        #pragma unroll
        for (int nf = 0; nf < 6; ++nf) {
            const int c = wn * 96 + nf * 16 + mloc;
            #pragma unroll
            for (int j = 0; j < 4; ++j) {
                int p = p0 + wm * 64 + mf * 16 + (lane >> 4) * 4 + j;
                out[(size_t)p * CIN + c] = acc[mf][nf][j] + bcol[nf];
            }
        }
    }
}

// ============================================================
extern "C" void kernel_launch(void* const* d_in, const int* in_sizes, int n_in,
                              void* d_out, int out_size, void* d_ws, size_t ws_size,
                              hipStream_t stream)
{
    const float* x   = (const float*)d_in[0];
    const float* Wd  = (const float*)d_in[1];
    const float* bd  = (const float*)d_in[2];
    const float* Wm1 = (const float*)d_in[3];
    const float* bm1 = (const float*)d_in[4];
    const float* Wm2 = (const float*)d_in[5];
    const float* bm2 = (const float*)d_in[6];
    const float* Wh  = (const float*)d_in[7];
    const float* bh  = (const float*)d_in[8];
    const float* emb = (const float*)d_in[9];
    const float* Wu  = (const float*)d_in[10];
    const float* bu  = (const float*)d_in[11];
    float* out = (float*)d_out;

    char* ws = (char*)d_ws;
    __half*   xd    = (__half*)(ws + XD_OFF);
    __half*   ybuf  = (__half*)(ws + Y_OFF);
    __half*   wperm = (__half*)(ws + WP_OFF);
    float*    hsum  = (float*)(ws + HS_OFF);
    float*    z     = (float*)(ws + Z_OFF);
    _Float16* Wt    = (_Float16*)(ws + WP_OFF);   // transient, consumed before k2b
    _Float16* WuT   = (_Float16*)(ws + WUT_OFF);

    hipMemsetAsync(hsum, 0, 64 * 64 * sizeof(float), stream);

    k0_wcvt<<<384, 256, 0, stream>>>(Wm1, Wd, Wu, Wt, WuT);
    k1_mfma<<<392, 512, 0, stream>>>(x, Wt, bm1, bd, hsum, xd);
    k2a_prompt<<<16, 256, 0, stream>>>(hsum, Wm2, bm2, emb, z);
    k2b_hyper<<<324, 256, 0, stream>>>(z, Wh, bh, wperm);
    k3_mfma<<<448, 256, 0, stream>>>(xd, wperm, ybuf);
    k4_mfma<<<392, 512, 0, stream>>>(ybuf, WuT, bu, out);
}

// Round 8
// 141.074 us; speedup vs baseline: 1.5979x; 1.0714x over previous
//
#include <hip/hip_runtime.h>
#include <hip/hip_fp16.h>

// ---------------- problem constants ----------------
#define BATCH 64
#define HH    28
#define WW2   28
#define HWPX  784          // 28*28
#define PTOT  50176        // 64*784
#define CIN   384
#define DIM   96
#define MDIM  64
#define JTOT  82944        // DIM*DIM*9
#define WSAMP 82944        // per-sample conv weights (96*864)

// ws layout (bytes)
#define XD_OFF 0u                       // P*96 f16 = 9,633,792
#define Y_OFF  9633792u                 // P*96 f16
#define WP_OFF 19267584u                // 64*82944 f16 = 10,616,832
#define HS_OFF 29884416u                // 64*64 f32
#define Z_OFF  29900800u                // 64*64 f32
#define WUT_OFF 29917184u               // 384*96 f16 = 73,728
// Wt (f16 [160][384] = 122,880 B) lives at WP_OFF: consumed by k1 BEFORE
// k2b overwrites the wperm region. Single stream -> deterministic.

typedef _Float16 f16x8 __attribute__((ext_vector_type(8)));
typedef _Float16 f16x4 __attribute__((ext_vector_type(4)));
typedef float f32x4 __attribute__((ext_vector_type(4)));

__device__ __forceinline__ float qgelu(float v) {
    return v / (1.f + __expf(-1.702f * v));
}

// ============================================================
// K0: convert [Wm1 | Wd] -> Wt f16 [o=160][k=384]
//     and Wu [96][384] -> WuT f16 [c=384][d=96]
// ============================================================
__global__ void k0_wcvt(const float* __restrict__ Wm1,
                        const float* __restrict__ Wd,
                        const float* __restrict__ Wu,
                        _Float16* __restrict__ Wt,
                        _Float16* __restrict__ WuT)
{
    int i = blockIdx.x * 256 + threadIdx.x;   // < 98304
    if (i < 61440) {
        int o = i / CIN, k = i - o * CIN;
        float v = (o < MDIM) ? Wm1[k * MDIM + o] : Wd[k * DIM + (o - MDIM)];
        Wt[i] = (_Float16)v;
    } else {
        int j = i - 61440;                    // < 36864
        int c = j / DIM, d = j - c * DIM;
        WuT[j] = (_Float16)Wu[d * CIN + c];
    }
}

// ============================================================
// K1: MFMA GEMM  C[P,160] = f16(x)[P,384] @ Wt^T, fused epilogues:
//   cols 0..63  : relu(+bm1) -> per-sample sum -> hsum (atomics)
//   cols 64..159: quick_gelu(+bd) -> xd f16
// v6: occupancy fix. M=64 tile, grid 784 (3.06 blk/CU), block 512
// (8 waves: 4m x 2n, each wave 1 mf x 5 nf). 6272 total waves = 24.5/CU
// (2x all previous variants). r3's proven single-buffer staging flow.
// LDS 18.4 KB -> 4+ blocks/CU resident; independent blocks overlap
// each other's barrier stalls.
// ============================================================
__global__ __launch_bounds__(512, 6) void k1_mfma(
    const float* __restrict__ x, const _Float16* __restrict__ Wt,
    const float* __restrict__ bm1, const float* __restrict__ bd,
    float* __restrict__ hsum, __half* __restrict__ xd)
{
    __shared__ char smem[18432];
    _Float16* As  = (_Float16*)smem;               // [64][40]  (5120 B)
    _Float16* Bs  = (_Float16*)(smem + 5120);      // [160][40] (12800 B)
    float*   hred = (float*)(smem + 17920);        // [2][64]   (512 B)
    _Float16* xds = (_Float16*)smem;               // epilogue [64][96]

    const int t = threadIdx.x;
    const int p0 = blockIdx.x * 64;
    const int lane = t & 63, w = t >> 6;
    const int wm = w >> 1, wn = w & 1;             // 4m x 2n wave grid
    const int rl = lane & 15, q = lane >> 4;

    // staging indices
    const int arow = t >> 3, aq = t & 7;           // A: 64 rows, 8 thr/row
    const int brow = t >> 2, bq = t & 3;           // B: rows 0..127 (+128 t<128)

    const float*    ag  = x + (size_t)(p0 + arow) * CIN + aq * 4;
    const _Float16* bg0 = Wt + brow * CIN + bq * 8;
    const _Float16* bg1 = Wt + (brow + 128) * CIN + bq * 8;

    float4 ra;
    uint4  rb0, rb1;

#define LOADC(kc_) do {                                           \
    ra  = *(const float4*)(ag + (kc_) * 32);                      \
    rb0 = *(const uint4*)(bg0 + (kc_) * 32);                      \
    if (t < 128) rb1 = *(const uint4*)(bg1 + (kc_) * 32);         \
} while (0)

#define WRITEC() do {                                             \
    f16x4 h;                                                      \
    h[0] = (_Float16)ra.x; h[1] = (_Float16)ra.y;                 \
    h[2] = (_Float16)ra.z; h[3] = (_Float16)ra.w;                 \
    *(f16x4*)(As + arow * 40 + aq * 4) = h;                       \
    *(uint4*)(Bs + brow * 40 + bq * 8) = rb0;                     \
    if (t < 128)                                                  \
        *(uint4*)(Bs + (brow + 128) * 40 + bq * 8) = rb1;         \
} while (0)

    f32x4 acc[5];
    #pragma unroll
    for (int nf = 0; nf < 5; ++nf) acc[nf] = (f32x4){0.f, 0.f, 0.f, 0.f};

    LOADC(0);

    #pragma unroll
    for (int kc = 0; kc < 12; ++kc) {
        WRITEC();
        __syncthreads();

        if (kc + 1 < 12) LOADC(kc + 1);    // in flight during MFMA phase

        f16x8 av, bv[5];
        av = *(f16x8*)(As + (wm * 16 + rl) * 40 + q * 8);
        #pragma unroll
        for (int nf = 0; nf < 5; ++nf)
            bv[nf] = *(f16x8*)(Bs + (wn * 80 + nf * 16 + rl) * 40 + q * 8);

        #pragma unroll
        for (int nf = 0; nf < 5; ++nf)
            acc[nf] = __builtin_amdgcn_mfma_f32_16x16x32_f16(
                av, bv[nf], acc[nf], 0, 0, 0);

        __syncthreads();
    }
#undef LOADC
#undef WRITEC

    // ---- epilogue ----
    if (t < 128) hred[t] = 0.f;
    __syncthreads();

    const int s0 = p0 / HWPX, s_last = (p0 + 63) / HWPX;
    #pragma unroll
    for (int nf = 0; nf < 5; ++nf) {
        const int col = wn * 80 + nf * 16 + rl;
        #pragma unroll
        for (int j = 0; j < 4; ++j) {
            const int rr = wm * 16 + q * 4 + j;
            float v = acc[nf][j];
            if (col < 64) {
                v = fmaxf(v + bm1[col], 0.f);
                int sloc = (p0 + rr) / HWPX - s0;
                atomicAdd(&hred[sloc * 64 + col], v);
            } else {
                int e = col - 64;
                xds[rr * 96 + e] = (_Float16)qgelu(v + bd[e]);
            }
        }
    }
    __syncthreads();

    if (t < 128) {
        int sloc = t >> 6, col = t & 63, s = s0 + sloc;
        if (s <= s_last) atomicAdd(&hsum[s * 64 + col], hred[t]);
    }
    // 64 rows x 96 f16 = 768 uint4, 512 threads
    {
        *(uint4*)((__half*)xd + (size_t)p0 * 96 + t * 8) = *(uint4*)(xds + t * 8);
        if (t < 256)
            *(uint4*)((__half*)xd + (size_t)p0 * 96 + (t + 512) * 8) =
                *(uint4*)(xds + (t + 512) * 8);
    }
}

// ============================================================
// K2a: z[b][m] = emb[m] + (hsum[b]/784)@Wm2 + bm2[m]
// ============================================================
__global__ void k2a_prompt(const float* __restrict__ hsum,
                           const float* __restrict__ Wm2,
                           const float* __restrict__ bm2,
                           const float* __restrict__ emb,
                           float* __restrict__ z)
{
    int idx = blockIdx.x * 256 + threadIdx.x;   // 4096
    int b = idx >> 6, m = idx & 63;
    float acc = 0.f;
    #pragma unroll 8
    for (int d = 0; d < 64; ++d) acc += hsum[b * 64 + d] * Wm2[d * 64 + m];
    z[idx] = emb[m] + acc * (1.f / 784.f) + bm2[m];
}

// ============================================================
// K2b: wflat[b][j] = z[b]@Wh[:,j] + bh[j], stored PERMUTED as
//      wperm[b][o][t9][i] (f16).  grid 324, block 256.
// ============================================================
__global__ __launch_bounds__(256) void k2b_hyper(
    const float* __restrict__ z, const float* __restrict__ Wh,
    const float* __restrict__ bh, __half* __restrict__ wperm)
{
    __shared__ float zs[4096];
    const int t = threadIdx.x;
    for (int idx = t; idx < 4096; idx += 256) zs[idx] = z[idx];
    const int j = blockIdx.x * 256 + t;
    float wh[64];
    #pragma unroll 8
    for (int m = 0; m < 64; ++m) wh[m] = Wh[(size_t)m * JTOT + j];
    __syncthreads();

    const int o = j / 864, rem = j % 864;
    const int i = rem / 9, t9 = rem % 9;
    const int base = o * 864 + t9 * 96 + i;
    const float bj = bh[j];
    for (int b = 0; b < 64; ++b) {
        float a = bj;
        const float4* zz = (const float4*)(zs + b * 64);
        #pragma unroll
        for (int m4 = 0; m4 < 16; ++m4) {
            float4 v = zz[m4];
            a += v.x * wh[4 * m4] + v.y * wh[4 * m4 + 1] +
                 v.z * wh[4 * m4 + 2] + v.w * wh[4 * m4 + 3];
        }
        wperm[(size_t)b * WSAMP + base] = __float2half(a);
    }
}

// ============================================================
// K3: MFMA implicit-GEMM grouped 3x3 conv + quick_gelu.
// grid 448 (XCD-grouped swizzle), block 256 (4 waves, 2m x 2n).
// ============================================================
__global__ __launch_bounds__(256) void k3_mfma(
    const __half* __restrict__ xd, const __half* __restrict__ wperm,
    __half* __restrict__ y)
{
    __shared__ __half sm[17600];                 // 35,200 B
    const int t = threadIdx.x;

    const int n = blockIdx.x;                    // 448
    const int xcd = n & 7, jj0 = n >> 3;         // jj0 < 56
    const int b = xcd * 8 + jj0 / 7;
    const int rt = jj0 % 7;
    const int h0 = rt * 4;

    if (t < 16) *(uint4*)(sm + 17472 + t * 8) = uint4{0u, 0u, 0u, 0u};
    for (int idx = t; idx < 2016; idx += 256) {
        int pix = idx / 12, q = idx - pix * 12;
        int r = pix / 28, col = pix - r * 28;
        int g = h0 - 1 + r;
        uint4 v = {0u, 0u, 0u, 0u};
        if ((unsigned)g < 28u)
            v = *(const uint4*)(xd + (size_t)(b * HWPX + g * 28 + col) * 96 + q * 8);
        *(uint4*)(sm + pix * 104 + q * 8) = v;
    }
    __syncthreads();

    const int lane = t & 63, w = t >> 6;
    const int wm = w >> 1, wn = w & 1;
    const int mloc = lane & 15, klo = (lane >> 4) * 8;
    const int base_m = wm * 64;

    int oh_[4], ow_[4]; bool pv[4];
    #pragma unroll
    for (int mf = 0; mf < 4; ++mf) {
        int p = base_m + mf * 16 + mloc;
        pv[mf] = (p < 112);
        int pp = pv[mf] ? p : 0;
        oh_[mf] = pp / 28; ow_[mf] = pp - oh_[mf] * 28;
    }
    const __half* wp = wperm + (size_t)b * WSAMP + (wn * 48 + mloc) * 864 + klo;

    f32x4 acc[4][3];
    #pragma unroll
    for (int mf = 0; mf < 4; ++mf)
        #pragma unroll
        for (int nf = 0; nf < 3; ++nf) acc[mf][nf] = (f32x4){0.f, 0.f, 0.f, 0.f};

    #pragma unroll
    for (int kh = 0; kh < 3; ++kh) {
        #pragma unroll
        for (int kw = 0; kw < 3; ++kw) {
            const int t9 = kh * 3 + kw;
            int abase[4];
            #pragma unroll
            for (int mf = 0; mf < 4; ++mf) {
                int iw = ow_[mf] + kw - 1;
                bool valid = pv[mf] && ((unsigned)iw < 28u);
                abase[mf] = valid ? ((oh_[mf] + kh) * 28 + iw) * 104 + klo
                                  : 17472 + klo;
            }
            #pragma unroll
            for (int ic = 0; ic < 3; ++ic) {
                f16x8 av[4], bv[3];
                #pragma unroll
                for (int nf = 0; nf < 3; ++nf)
                    bv[nf] = *(const f16x8*)(wp + nf * 13824 + t9 * 96 + ic * 32);
                #pragma unroll
                for (int mf = 0; mf < 4; ++mf)
                    av[mf] = *(const f16x8*)(sm + abase[mf] + ic * 32);
                #pragma unroll
                for (int mf = 0; mf < 4; ++mf)
                    #pragma unroll
                    for (int nf = 0; nf < 3; ++nf)
                        acc[mf][nf] = __builtin_amdgcn_mfma_f32_16x16x32_f16(
                            av[mf], bv[nf], acc[mf][nf], 0, 0, 0);
            }
        }
    }
    __syncthreads();

    #pragma unroll
    for (int mf = 0; mf < 4; ++mf) {
        #pragma unroll
        for (int nf = 0; nf < 3; ++nf) {
            const int o = wn * 48 + nf * 16 + mloc;
            #pragma unroll
            for (int j = 0; j < 4; ++j) {
                int p = base_m + mf * 16 + (lane >> 4) * 4 + j;
                if (p < 112)
                    sm[p * 104 + o] = __float2half(qgelu(acc[mf][nf][j]));
            }
        }
    }
    __syncthreads();
    for (int idx = t; idx < 1344; idx += 256) {
        int pix = idx / 12, q = idx - pix * 12;
        *(uint4*)(y + (size_t)(b * HWPX + h0 * 28 + pix) * 96 + q * 8) =
            *(uint4*)(sm + pix * 104 + q * 8);
    }
}

// ============================================================
// K4: MFMA GEMM  out[P,384] = y[P,96] @ Wu + bu (f32 out).
// grid 392, block 512 (8 waves 2m x 4n). Tile M=128, N=384, K=96.
// ============================================================
__global__ __launch_bounds__(512, 2) void k4_mfma(
    const __half* __restrict__ y, const _Float16* __restrict__ WuT,
    const float* __restrict__ bu, float* __restrict__ out)
{
    __shared__ __half ys[128 * 104];             // 26,624 B
    const int t = threadIdx.x;
    const int p0 = blockIdx.x * 128;

    #pragma unroll
    for (int i = 0; i < 3; ++i) {
        int idx = t + i * 512;                   // < 1536
        int pix = idx / 12, q = idx - pix * 12;
        *(uint4*)(ys + pix * 104 + q * 8) =
            *(const uint4*)(y + (size_t)(p0 + pix) * 96 + q * 8);
    }

    const int lane = t & 63, w = t >> 6;
    const int wm = w >> 2, wn = w & 3;           // 2m x 4n
    const int mloc = lane & 15, klo = (lane >> 4) * 8;

    float bcol[6];
    #pragma unroll
    for (int nf = 0; nf < 6; ++nf) bcol[nf] = bu[wn * 96 + nf * 16 + mloc];
    __syncthreads();

    f32x4 acc[4][6];
    #pragma unroll
    for (int mf = 0; mf < 4; ++mf)
        #pragma unroll
        for (int nf = 0; nf < 6; ++nf) acc[mf][nf] = (f32x4){0.f, 0.f, 0.f, 0.f};

    #pragma unroll
    for (int kc = 0; kc < 3; ++kc) {
        f16x8 av[4], bv[6];
        #pragma unroll
        for (int nf = 0; nf < 6; ++nf)
            bv[nf] = *(const f16x8*)(WuT + (wn * 96 + nf * 16 + mloc) * 96 + kc * 32 + klo);
        #pragma unroll
        for (int mf = 0; mf < 4; ++mf)
            av[mf] = *(const f16x8*)(ys + (wm * 64 + mf * 16 + mloc) * 104 + kc * 32 + klo);
        #pragma unroll
        for (int mf = 0; mf < 4; ++mf)
            #pragma unroll
            for (int nf = 0; nf < 6; ++nf)
                acc[mf][nf] = __builtin_amdgcn_mfma_f32_16x16x32_f16(
                    av[mf], bv[nf], acc[mf][nf], 0, 0, 0);
    }

    #pragma unroll
    for (int mf = 0; mf < 4; ++mf) {
        #pragma unroll
        for (int nf = 0; nf < 6; ++nf) {
            const int c = wn * 96 + nf * 16 + mloc;
            #pragma unroll
            for (int j = 0; j < 4; ++j) {
                int p = p0 + wm * 64 + mf * 16 + (lane >> 4) * 4 + j;
                out[(size_t)p * CIN + c] = acc[mf][nf][j] + bcol[nf];
            }
        }
    }
}

// ============================================================
extern "C" void kernel_launch(void* const* d_in, const int* in_sizes, int n_in,
                              void* d_out, int out_size, void* d_ws, size_t ws_size,
                              hipStream_t stream)
{
    const float* x   = (const float*)d_in[0];
    const float* Wd  = (const float*)d_in[1];
    const float* bd  = (const float*)d_in[2];
    const float* Wm1 = (const float*)d_in[3];
    const float* bm1 = (const float*)d_in[4];
    const float* Wm2 = (const float*)d_in[5];
    const float* bm2 = (const float*)d_in[6];
    const float* Wh  = (const float*)d_in[7];
    const float* bh  = (const float*)d_in[8];
    const float* emb = (const float*)d_in[9];
    const float* Wu  = (const float*)d_in[10];
    const float* bu  = (const float*)d_in[11];
    float* out = (float*)d_out;

    char* ws = (char*)d_ws;
    __half*   xd    = (__half*)(ws + XD_OFF);
    __half*   ybuf  = (__half*)(ws + Y_OFF);
    __half*   wperm = (__half*)(ws + WP_OFF);
    float*    hsum  = (float*)(ws + HS_OFF);
    float*    z     = (float*)(ws + Z_OFF);
    _Float16* Wt    = (_Float16*)(ws + WP_OFF);   // transient, consumed before k2b
    _Float16* WuT   = (_Float16*)(ws + WUT_OFF);

    hipMemsetAsync(hsum, 0, 64 * 64 * sizeof(float), stream);

    k0_wcvt<<<384, 256, 0, stream>>>(Wm1, Wd, Wu, Wt, WuT);
    k1_mfma<<<784, 512, 0, stream>>>(x, Wt, bm1, bd, hsum, xd);
    k2a_prompt<<<16, 256, 0, stream>>>(hsum, Wm2, bm2, emb, z);
    k2b_hyper<<<324, 256, 0, stream>>>(z, Wh, bh, wperm);
    k3_mfma<<<448, 256, 0, stream>>>(xd, wperm, ybuf);
    k4_mfma<<<392, 512, 0, stream>>>(ybuf, WuT, bu, out);
}